// Round 2
// baseline (121.457 us; speedup 1.0000x reference)
//
#include <hip/hip_runtime.h>

// out = x @ (Wc + Wn) + b   -- gamma/segment ops in the reference are dead code.
// x: [100000,128] f32, Wc/Wn: [128,128] f32, b: [128] f32, out: [100000,128] f32.
//
// R2: back to the R0 two-kernel split (ws poison is unconditional -> using ws
// is free, and per-block W staging from Wc/Wn was a ~6us VALU regression).
// Changes vs R0:
//   * x->bf16 via scalar __bf16 casts (compiler fuses to v_cvt_pk_bf16_f32,
//     RNE; replaces the 4-op f2bf bit-twiddle -> ~8x fewer conversion VALU ops)
//   * swapped MFMA operands: D[n][m] -> epilogue is 16x global_store_dwordx4
//   * __launch_bounds__(256,4): pin 4 waves/EU (matches the 4-block/CU LDS cap)

#define NROWS 100000

typedef __attribute__((ext_vector_type(8))) __bf16 bf16x8;
typedef __attribute__((ext_vector_type(8))) unsigned short u16x8;
typedef __attribute__((ext_vector_type(4))) float f32x4;

__device__ __forceinline__ bf16x8 pack8(const float4 lo, const float4 hi) {
    bf16x8 r;
    r[0] = (__bf16)lo.x; r[1] = (__bf16)lo.y; r[2] = (__bf16)lo.z; r[3] = (__bf16)lo.w;
    r[4] = (__bf16)hi.x; r[5] = (__bf16)hi.y; r[6] = (__bf16)hi.z; r[7] = (__bf16)hi.w;
    return r;
}

// Build Wt[n][k] = bf16(Wc[k][n] + Wn[k][n]) in workspace (transposed so the
// MFMA A-fragment read is 8 contiguous bf16 = one ds_read_b128).
__global__ void prep_wt(const float* __restrict__ Wc, const float* __restrict__ Wn,
                        unsigned short* __restrict__ wt) {
    int i = blockIdx.x * 256 + threadIdx.x;   // 16384 outputs, wt laid out [n][k]
    int n = i >> 7, k = i & 127;
    __bf16 v = (__bf16)(Wc[k * 128 + n] + Wn[k * 128 + n]);
    wt[i] = __builtin_bit_cast(unsigned short, v);
}

// 128 rows per block, 4 waves x 32 rows, full N=128 / K=128 per block.
__global__ __launch_bounds__(256, 4) void gemm_bias(
    const float* __restrict__ x, const unsigned short* __restrict__ wt,
    const float* __restrict__ bias_g, float* __restrict__ out) {

    // 136-short row stride: 16B-aligned rows (272 = 17*16) and only 2-way
    // bank aliasing on the fragment reads (free per m136).
    __shared__ __align__(16) unsigned short sWt[128 * 136];

    const int tid = threadIdx.x;
    // Stage Wt (32 KB) into LDS: 2048 x 16B chunks, coalesced global reads.
    #pragma unroll
    for (int it = 0; it < 8; ++it) {
        int idx8 = it * 256 + tid;           // chunk id, 16 chunks per row
        int n = idx8 >> 4;
        int k = (idx8 & 15) << 3;
        *(u16x8*)&sWt[n * 136 + k] = *(const u16x8*)(wt + (idx8 << 3));
    }
    __syncthreads();

    const int wave = tid >> 6;
    const int lane = tid & 63;
    const int quad = lane >> 4;
    const int l16  = lane & 15;

    const long rowbase = (long)blockIdx.x * 128 + wave * 32;
    if (rowbase >= NROWS) return;   // 100000 % 32 == 0: whole waves drop out

    // bias for n = ct*16 + quad*4 + r  -> float4 per ct
    float4 bv[8];
    #pragma unroll
    for (int ct = 0; ct < 8; ++ct)
        bv[ct] = *(const float4*)(bias_g + ct * 16 + quad * 4);

    f32x4 acc[2][8] = {};   // [m-subtile][n-tile]; D[n][m] layout (swapped ops)

    // x fragments (MFMA B-operand): B[k = quad*8+j][m = lane&15]
    const float* xr0 = x + (rowbase + l16) * 128;
    const float* xr1 = xr0 + 16 * 128;

    #pragma unroll
    for (int kc = 0; kc < 4; ++kc) {
        const int ko = kc * 32 + quad * 8;
        float4 a0lo = *(const float4*)(xr0 + ko);
        float4 a0hi = *(const float4*)(xr0 + ko + 4);
        float4 a1lo = *(const float4*)(xr1 + ko);
        float4 a1hi = *(const float4*)(xr1 + ko + 4);
        bf16x8 a0 = pack8(a0lo, a0hi);
        bf16x8 a1 = pack8(a1lo, a1hi);
        #pragma unroll
        for (int ct = 0; ct < 8; ++ct) {
            // Wt fragment (MFMA A-operand): A[n = lane&15][k = quad*8+j]
            bf16x8 wf = *(const bf16x8*)&sWt[(ct * 16 + l16) * 136 + ko];
            // D[i=n][j=m]: out[m][n] = sum_k x[m][k] * Wt[n][k]
            acc[0][ct] = __builtin_amdgcn_mfma_f32_16x16x32_bf16(wf, a0, acc[0][ct], 0, 0, 0);
            acc[1][ct] = __builtin_amdgcn_mfma_f32_16x16x32_bf16(wf, a1, acc[1][ct], 0, 0, 0);
        }
    }

    // C/D layout: col(j=m) = lane&15, row(i=n) = quad*4 + reg  [m89/m91]
    // => each lane's 4 regs are 4 consecutive output columns: dwordx4 stores.
    #pragma unroll
    for (int mt = 0; mt < 2; ++mt) {
        float* orow = out + (rowbase + mt * 16 + l16) * 128;
        #pragma unroll
        for (int ct = 0; ct < 8; ++ct) {
            float4 st4;
            st4.x = acc[mt][ct][0] + bv[ct].x;
            st4.y = acc[mt][ct][1] + bv[ct].y;
            st4.z = acc[mt][ct][2] + bv[ct].z;
            st4.w = acc[mt][ct][3] + bv[ct].w;
            *(float4*)(orow + ct * 16 + quad * 4) = st4;
        }
    }
}

extern "C" void kernel_launch(void* const* d_in, const int* in_sizes, int n_in,
                              void* d_out, int out_size, void* d_ws, size_t ws_size,
                              hipStream_t stream) {
    const float* x  = (const float*)d_in[0];
    // d_in[1] = edge_index (int64) -- dead code in the reference, never read.
    const float* Wc = (const float*)d_in[2];
    const float* Wn = (const float*)d_in[3];
    const float* b  = (const float*)d_in[4];
    unsigned short* wt = (unsigned short*)d_ws;   // 32 KB scratch
    float* out = (float*)d_out;

    prep_wt<<<64, 256, 0, stream>>>(Wc, Wn, wt);
    const int nblocks = (NROWS + 127) / 128;      // 782
    gemm_bias<<<nblocks, 256, 0, stream>>>(x, wt, b, out);
}

// Round 3
// 114.817 us; speedup vs baseline: 1.0578x; 1.0578x over previous
//
#include <hip/hip_runtime.h>

// out = x @ (Wc + Wn) + b   -- gamma/segment ops in the reference are dead code.
// x: [100000,128] f32, Wc/Wn: [128,128] f32, b: [128] f32, out: [100000,128] f32.
//
// R3: R0 structure (two-kernel split; ws poison is unconditional so ws use is
// free) + the two R2 wins, minus the R2 regressions:
//   * x->bf16 via scalar __bf16 casts (v_cvt_pk_bf16_f32, RNE) -- keep
//   * swapped MFMA operands: D[n][m] -> 16x global_store_dwordx4 -- keep
//   * NO min-waves launch bound (R2's (256,4) capped VGPR=128 -> spills)
//   * bias float4 loads moved AFTER the K-loop (epilogue-only live range)

#define NROWS 100000

typedef __attribute__((ext_vector_type(8))) __bf16 bf16x8;
typedef __attribute__((ext_vector_type(8))) unsigned short u16x8;
typedef __attribute__((ext_vector_type(4))) float f32x4;

__device__ __forceinline__ bf16x8 pack8(const float4 lo, const float4 hi) {
    bf16x8 r;
    r[0] = (__bf16)lo.x; r[1] = (__bf16)lo.y; r[2] = (__bf16)lo.z; r[3] = (__bf16)lo.w;
    r[4] = (__bf16)hi.x; r[5] = (__bf16)hi.y; r[6] = (__bf16)hi.z; r[7] = (__bf16)hi.w;
    return r;
}

// Build Wt[n][k] = bf16(Wc[k][n] + Wn[k][n]) in workspace (transposed so the
// MFMA A-fragment read is 8 contiguous bf16 = one ds_read_b128).
__global__ void prep_wt(const float* __restrict__ Wc, const float* __restrict__ Wn,
                        unsigned short* __restrict__ wt) {
    int i = blockIdx.x * 256 + threadIdx.x;   // 16384 outputs, wt laid out [n][k]
    int n = i >> 7, k = i & 127;
    __bf16 v = (__bf16)(Wc[k * 128 + n] + Wn[k * 128 + n]);
    wt[i] = __builtin_bit_cast(unsigned short, v);
}

// 128 rows per block, 4 waves x 32 rows, full N=128 / K=128 per block.
__global__ __launch_bounds__(256) void gemm_bias(
    const float* __restrict__ x, const unsigned short* __restrict__ wt,
    const float* __restrict__ bias_g, float* __restrict__ out) {

    // 136-short row stride: 16B-aligned rows (272 = 17*16) and only 2-way
    // bank aliasing on the fragment reads (free per m136).
    __shared__ __align__(16) unsigned short sWt[128 * 136];

    const int tid = threadIdx.x;
    // Stage Wt (32 KB) into LDS: 2048 x 16B chunks, coalesced global reads.
    #pragma unroll
    for (int it = 0; it < 8; ++it) {
        int idx8 = it * 256 + tid;           // chunk id, 16 chunks per row
        int n = idx8 >> 4;
        int k = (idx8 & 15) << 3;
        *(u16x8*)&sWt[n * 136 + k] = *(const u16x8*)(wt + (idx8 << 3));
    }
    __syncthreads();

    const int wave = tid >> 6;
    const int lane = tid & 63;
    const int quad = lane >> 4;
    const int l16  = lane & 15;

    const long rowbase = (long)blockIdx.x * 128 + wave * 32;
    if (rowbase >= NROWS) return;   // 100000 % 32 == 0: whole waves drop out

    f32x4 acc[2][8] = {};   // [m-subtile][n-tile]; D[n][m] layout (swapped ops)

    // x fragments (MFMA B-operand): B[k = quad*8+j][m = lane&15]
    const float* xr0 = x + (rowbase + l16) * 128;
    const float* xr1 = xr0 + 16 * 128;

    #pragma unroll
    for (int kc = 0; kc < 4; ++kc) {
        const int ko = kc * 32 + quad * 8;
        float4 a0lo = *(const float4*)(xr0 + ko);
        float4 a0hi = *(const float4*)(xr0 + ko + 4);
        float4 a1lo = *(const float4*)(xr1 + ko);
        float4 a1hi = *(const float4*)(xr1 + ko + 4);
        bf16x8 a0 = pack8(a0lo, a0hi);
        bf16x8 a1 = pack8(a1lo, a1hi);
        #pragma unroll
        for (int ct = 0; ct < 8; ++ct) {
            // Wt fragment (MFMA A-operand): A[n = lane&15][k = quad*8+j]
            bf16x8 wf = *(const bf16x8*)&sWt[(ct * 16 + l16) * 136 + ko];
            // D[i=n][j=m]: out[m][n] = sum_k x[m][k] * Wt[n][k]
            acc[0][ct] = __builtin_amdgcn_mfma_f32_16x16x32_bf16(wf, a0, acc[0][ct], 0, 0, 0);
            acc[1][ct] = __builtin_amdgcn_mfma_f32_16x16x32_bf16(wf, a1, acc[1][ct], 0, 0, 0);
        }
    }

    // Bias loaded HERE so its live range is epilogue-only (R2 loaded it before
    // the K-loop -> +24 VGPRs of loop-long pressure).
    float4 bv[8];
    #pragma unroll
    for (int ct = 0; ct < 8; ++ct)
        bv[ct] = *(const float4*)(bias_g + ct * 16 + quad * 4);

    // C/D layout: col(j=m) = lane&15, row(i=n) = quad*4 + reg  [m89/m91]
    // => each lane's 4 regs are 4 consecutive output columns: dwordx4 stores,
    // and each instruction writes full 64B lines (4 quads tile 64B per row).
    #pragma unroll
    for (int mt = 0; mt < 2; ++mt) {
        float* orow = out + (rowbase + mt * 16 + l16) * 128;
        #pragma unroll
        for (int ct = 0; ct < 8; ++ct) {
            float4 st4;
            st4.x = acc[mt][ct][0] + bv[ct].x;
            st4.y = acc[mt][ct][1] + bv[ct].y;
            st4.z = acc[mt][ct][2] + bv[ct].z;
            st4.w = acc[mt][ct][3] + bv[ct].w;
            *(float4*)(orow + ct * 16 + quad * 4) = st4;
        }
    }
}

extern "C" void kernel_launch(void* const* d_in, const int* in_sizes, int n_in,
                              void* d_out, int out_size, void* d_ws, size_t ws_size,
                              hipStream_t stream) {
    const float* x  = (const float*)d_in[0];
    // d_in[1] = edge_index (int64) -- dead code in the reference, never read.
    const float* Wc = (const float*)d_in[2];
    const float* Wn = (const float*)d_in[3];
    const float* b  = (const float*)d_in[4];
    unsigned short* wt = (unsigned short*)d_ws;   // 32 KB scratch
    float* out = (float*)d_out;

    prep_wt<<<64, 256, 0, stream>>>(Wc, Wn, wt);
    const int nblocks = (NROWS + 127) / 128;      // 782
    gemm_bias<<<nblocks, 256, 0, stream>>>(x, wt, b, out);
}